// Round 15
// baseline (128.239 us; speedup 1.0000x reference)
//
#include <hip/hip_runtime.h>
#include <stdint.h>

// BConv2d via MFMA i8 implicit GEMM (R10-verified math; 64-co waves).
// out = conv2d(sign(x), sign(w), pad=1) + b ; N=32, Cin=256, H=W=56, Cout=256, K=3.
//
// sign as i8 {+1,-1}, zero padding as i8 0 (exact). conv = 9 tap-shifted
// GEMMs, K=256, i32 acc via v_mfma_i32_32x32x32_i8. C/D layout:
// col=lane&31, row=(reg&3)+8*(reg>>2)+4*(lane>>5) (verified R8-R14).
//
// R14 lesson: launch_bounds caps regs but the scheduler targets the occupancy
// LDS ALLOWS (4 waves/SIMD at 512thr/68.6KB) and sinks all prefetches to fit
// 128 regs. R15: 256-thread blocks -> LDS caps occupancy at 2 blocks/CU =
// 2 waves/SIMD NATURALLY -> scheduler and the 256-reg budget agree.
// Each wave owns 64 co (2 cogs) x all 64 pixel-cols, 8 accs (128 AGPR) live:
//   - B fragment feeds 24 MFMAs (was 12) -> LDS pipe 54 -> 27 us
//   - A loaded once per (dw,c8), shared by both colblks -> A-L2 30 -> 15 us
//   - MFMA pipe (30.5 us) is now the top pipe.

#define NBATCH 32
#define CIN    256
#define COUT   256
#define HH     56
#define WW     56
#define HW     (HH*WW)          // 3136
#define NPIX   (NBATCH*HW)      // 100352

#define PW    58                // padded bit-image width/height
#define PROW  (PW*8)            // 464 words per padded row
#define PIMG  (PW*PW*8)         // 26912 words per padded image

#define XP_BYTES  ((size_t)NBATCH * PIMG * 4)  // 3,444,736 (16-aligned)
#define WQ_BYTES  ((size_t)9 * 8 * 256 * 32)   // 589,824

typedef int i32x4  __attribute__((ext_vector_type(4)));
typedef int i32x16 __attribute__((ext_vector_type(16)));

// ---- pack x bits: wave handles 64 channels (2 words) for 64 pixels
__global__ __launch_bounds__(256) void pack_x_kernel(
    const float* __restrict__ x, uint32_t* __restrict__ xp)
{
    int lane = threadIdx.x & 63;
    int wv   = threadIdx.x >> 6;               // 0..3 -> channel group
    int pix  = blockIdx.x * 64 + lane;         // 1568 blocks * 64 == NPIX
    int n  = pix / HW;
    int hw = pix - n * HW;
    int h  = hw / WW;
    int w_ = hw - h * WW;
    const float* xb = x + ((size_t)n * CIN + (size_t)wv * 64) * HW + hw;

    uint32_t w0 = 0, w1 = 0;
    #pragma unroll
    for (int j = 0; j < 32; ++j) {
        w0 |= (xb[(size_t)j * HW]        >= 0.0f ? 1u : 0u) << j;
        w1 |= (xb[(size_t)(j + 32) * HW] >= 0.0f ? 1u : 0u) << j;
    }
    uint32_t* dst = xp + (size_t)n * PIMG + (size_t)(h + 1) * PROW
                       + (size_t)(w_ + 1) * 8 + wv * 2;
    *(uint2*)dst = make_uint2(w0, w1);
}

// ---- pack w -> i8 {+1,-1}, layout wq[t][c8][co][slot], slot = ci&31
__global__ __launch_bounds__(256) void pack_w2_kernel(
    const float* __restrict__ w, int8_t* __restrict__ wq)
{
    int co = blockIdx.x, ci = threadIdx.x;
    const float* wb = w + ((size_t)co * CIN + ci) * 9;
    int c8 = ci >> 5, s = ci & 31;
    #pragma unroll
    for (int t = 0; t < 9; ++t) {
        wq[((size_t)(t * 8 + c8) * 256 + co) * 32 + s] =
            (wb[t] >= 0.0f) ? (int8_t)1 : (int8_t)-1;
    }
}

// ---- conv: 256 threads = 4 waves; wave wv owns co 64wv..64wv+63
#define MFMA(ACC, A, B) \
    ACC = __builtin_amdgcn_mfma_i32_32x32x32_i8(A, B, ACC, 0, 0, 0);

__global__ __launch_bounds__(256, 2) void bconv_kernel(
    const uint32_t* __restrict__ xp, const int8_t* __restrict__ wq,
    const float* __restrict__ bias, float* __restrict__ out)
{
    __shared__ __align__(16) int8_t xt[4][66][256];   // 67,584 B
    __shared__ float bsh[256];

    int bx = blockIdx.x;               // 0..895
    int n  = bx / 28;
    int hb = bx - n * 28;
    int h  = hb * 2;                   // output rows h, h+1
    int tid = threadIdx.x, lane = tid & 63, wv = tid >> 6;   // wv 0..3

    bsh[tid] = bias[tid];

    // expand packed sign bits -> i8 (+1/-1); borders & cols>=58 -> 0
    const uint32_t* xpb = xp + (size_t)n * PIMG;
    for (int e = tid; e < 4 * 66 * 64; e += 256) {   // 66 iters exactly
        int pr  = e / (66 * 64);
        int rem = e - pr * (66 * 64);
        int col = rem >> 6;
        int d   = rem & 63;            // output dword = 4 ci
        int prg = h + pr;              // padded global row
        bool val = (prg >= 1) & (prg <= 56) & (col >= 1) & (col <= 56);
        uint32_t wvv = 0;
        if (val) wvv = xpb[(size_t)prg * PROW + col * 8 + (d >> 3)];
        uint32_t nib = (wvv >> ((d & 7) * 4)) & 0xFu;
        uint32_t sp  = (nib * 0x00204081u) & 0x01010101u;   // bit k -> byte k
        uint32_t o   = val ? __builtin_amdgcn_perm(0u, 0x000001FFu, sp) : 0u;
        uint32_t ba  = (uint32_t)((((pr * 66 + col) << 8) | (d << 2))
                                  ^ ((col & 15) << 4));
        *(uint32_t*)((char*)&xt[0][0][0] + ba) = o;
    }
    __syncthreads();

    int l31  = lane & 31;
    int hi16 = (lane >> 5) << 4;
    // cog0 = 2wv (co = 64wv + l31), cog1 = 2wv+1 (co + 32)
    const char* wql0 = (const char*)wq + (size_t)(wv * 64 + l31) * 32 + hi16;
    const char* wql1 = wql0 + 1024;
    const char* xtb  = (const char*)&xt[0][0][0];

    // 8 accumulators: p=colblk0, q=colblk1; [cog][row]
    i32x16 p00 = {0}, p01 = {0}, p10 = {0}, p11 = {0};
    i32x16 q00 = {0}, q01 = {0}, q10 = {0}, q11 = {0};

    #pragma unroll 1
    for (int dw = 0; dw < 3; ++dw) {
        int col0 = l31 + dw;
        int sw   = (col0 & 15) << 4;           // (col0+32)&15 identical
        const char* xc0 = xtb + (col0 << 8);
        const char* xc1 = xc0 + (32 << 8);
        #pragma unroll
        for (int c8 = 0; c8 < 8; ++c8) {
            int sx = ((c8 << 5) + hi16) ^ sw;
            i32x4 b00 = *(const i32x4*)(xc0 + ((0 * 66) << 8) + sx);
            i32x4 b01 = *(const i32x4*)(xc0 + ((1 * 66) << 8) + sx);
            i32x4 b02 = *(const i32x4*)(xc0 + ((2 * 66) << 8) + sx);
            i32x4 b03 = *(const i32x4*)(xc0 + ((3 * 66) << 8) + sx);
            i32x4 b10 = *(const i32x4*)(xc1 + ((0 * 66) << 8) + sx);
            i32x4 b11 = *(const i32x4*)(xc1 + ((1 * 66) << 8) + sx);
            i32x4 b12 = *(const i32x4*)(xc1 + ((2 * 66) << 8) + sx);
            i32x4 b13 = *(const i32x4*)(xc1 + ((3 * 66) << 8) + sx);
            const char* wa0 = wql0 + (size_t)(dw * 8 + c8) * 8192;
            const char* wa1 = wql1 + (size_t)(dw * 8 + c8) * 8192;
            i32x4 a00 = *(const i32x4*)(wa0);
            i32x4 a01 = *(const i32x4*)(wa0 + 196608);
            i32x4 a02 = *(const i32x4*)(wa0 + 393216);
            i32x4 a10 = *(const i32x4*)(wa1);
            i32x4 a11 = *(const i32x4*)(wa1 + 196608);
            i32x4 a12 = *(const i32x4*)(wa1 + 393216);

            // colblk0: rows h (b_dh), h+1 (b_dh+1)
            MFMA(p00, a00, b00) MFMA(p01, a00, b01)
            MFMA(p10, a10, b00) MFMA(p11, a10, b01)
            MFMA(p00, a01, b01) MFMA(p01, a01, b02)
            MFMA(p10, a11, b01) MFMA(p11, a11, b02)
            MFMA(p00, a02, b02) MFMA(p01, a02, b03)
            MFMA(p10, a12, b02) MFMA(p11, a12, b03)
            // colblk1
            MFMA(q00, a00, b10) MFMA(q01, a00, b11)
            MFMA(q10, a10, b10) MFMA(q11, a10, b11)
            MFMA(q00, a01, b11) MFMA(q01, a01, b12)
            MFMA(q10, a11, b11) MFMA(q11, a11, b12)
            MFMA(q00, a02, b12) MFMA(q01, a02, b13)
            MFMA(q10, a12, b12) MFMA(q11, a12, b13)
        }
    }

    // epilogue: C col=pixel(l31 within colblk), row=(r&3)+8*(r>>2)+4*(lane>>5)
    #define EPI2(P0, P1, CG, PIXB) { \
        int pix = (PIXB) + l31; \
        if (pix < WW) { \
            float* op = out + (size_t)n * COUT * HW + (size_t)h * WW + pix; \
            _Pragma("unroll") \
            for (int r = 0; r < 16; ++r) { \
                int row = (r & 3) + 8 * (r >> 2) + ((lane >> 5) << 2); \
                int co  = ((2 * wv + (CG)) << 5) + row; \
                float bb = bsh[co]; \
                op[(size_t)co * HW]      = (float)P0[r] + bb; \
                op[(size_t)co * HW + WW] = (float)P1[r] + bb; \
            } \
        } }
    EPI2(p00, p01, 0, 0)
    EPI2(p10, p11, 1, 0)
    EPI2(q00, q01, 0, 32)
    EPI2(q10, q11, 1, 32)
    #undef EPI2
}

extern "C" void kernel_launch(void* const* d_in, const int* in_sizes, int n_in,
                              void* d_out, int out_size, void* d_ws, size_t ws_size,
                              hipStream_t stream) {
    const float* x = (const float*)d_in[0];
    const float* w = (const float*)d_in[1];
    const float* b = (const float*)d_in[2];
    float* out = (float*)d_out;

    uint32_t* xp = (uint32_t*)d_ws;
    int8_t*   wq = (int8_t*)((char*)d_ws + XP_BYTES);

    pack_x_kernel<<<NPIX / 64, 256, 0, stream>>>(x, xp);
    pack_w2_kernel<<<COUT, 256, 0, stream>>>(w, wq);

    bconv_kernel<<<NBATCH * (HH / 2), 256, 0, stream>>>(xp, wq, b, out);
}